// Round 1
// baseline (351.115 us; speedup 1.0000x reference)
//
#include <hip/hip_runtime.h>
#include <math.h>

#define CEPS 1e-9f

// x  : [4,56,56,8,32]  strides b:802816 h:14336 w:256 cin:32
// W  : [4,4,128,32]    (kh,kw,out_ch=ca,in_ch=ci)
// b  : [128]           bias per (c,a)
// out: [4,112,112,128] act
//
// out[n,p,q,ca] = sum over taps kh with (p+1-kh) even, i=(p+1-kh)/2 in [0,56)
//                 (and kw/j likewise) of sum_ci xt[n,i,j,ci]*W[kh,kw,ca,ci]
// votes[b',i'] = row n = b'*8+i' ; xt[n] = x[b=n&3, :, :, cin=n>>2, :]
// One wave per output pixel; block = 2x2 same-parity pixel tile.

__global__ __launch_bounds__(256, 3) void caps_deconv_routing(
    const float* __restrict__ x,
    const float* __restrict__ Wt,
    const float* __restrict__ bias,
    float* __restrict__ out)
{
    __shared__ __align__(16) float Wtap[2][4160];   // [buf][ci*130 + ca], pad 130 for bank-free b64
    __shared__ __align__(16) float xs[2304];        // [i][di][dj][ci] = i*288 + di*96 + dj*32 + ci

    const int t    = threadIdx.x;
    const int tile = blockIdx.x;            // 0..783
    const int tu   = tile / 28;
    const int tv   = tile - tu * 28;
    const int rh   = blockIdx.y >> 1;       // pixel parity (p&1)
    const int rw   = blockIdx.y & 1;        // (q&1)
    const int bp   = blockIdx.z;            // b'
    const int u0   = tu * 2, v0 = tv * 2;   // u = p>>1 base, tile covers u0..u0+1
    const int ibase = u0 - 1 + rh;
    const int jbase = v0 - 1 + rw;

    // ---- stage x tile: 8 rows x 3 di x 3 dj x 32 ci (zero-filled out of range) ----
    for (int it = 0; it < 3; ++it) {
        int idx = t + (it << 8);
        if (idx < 576) {
            int i    = idx / 72;
            int rem  = idx - i * 72;
            int di   = rem / 24;
            int rem2 = rem - di * 24;
            int dj   = rem2 >> 3;
            int ci4  = rem2 & 7;
            int gi = ibase + di, gj = jbase + dj;
            float4 v = make_float4(0.f, 0.f, 0.f, 0.f);
            if ((unsigned)gi < 56u && (unsigned)gj < 56u) {
                int n = bp * 8 + i;
                int b = n & 3, cin = n >> 2;
                v = *(const float4*)(x + b * 802816 + gi * 14336 + gj * 256 + cin * 32 + (ci4 << 2));
            }
            *(float4*)(xs + i * 288 + di * 96 + dj * 32 + (ci4 << 2)) = v;
        }
    }

    // ---- stage W tap 0 (tkh=0,tkw=0 -> kh=1-rh, kw=1-rw), transposed to [ci][ca] ----
    {
        const int kh = 1 - rh, kw = 1 - rw;
        const float* src = Wt + ((kh * 4 + kw) << 12);
        for (int it = 0; it < 4; ++it) {
            int idx = t + (it << 8);          // [0,1024): ca=idx>>3, ci4=idx&7
            int ca  = idx >> 3;
            int ci4 = idx & 7;
            float4 wv = *(const float4*)(src + (ca << 5) + (ci4 << 2));
            float* dst = &Wtap[0][(ci4 << 2) * 130 + ca];
            dst[0]   = wv.x;
            dst[130] = wv.y;
            dst[260] = wv.z;
            dst[390] = wv.w;
        }
    }
    __syncthreads();

    const int w  = t >> 6;          // wave = pixel within 2x2 tile
    const int l  = t & 63;          // lane: covers ca = 2l, 2l+1 ; c = l>>3
    const int uu = w >> 1;
    const int vv = w & 1;

    float2 vo[8];                   // votes[i][2 ca] in registers
    #pragma unroll
    for (int i = 0; i < 8; ++i) vo[i] = make_float2(0.f, 0.f);

    for (int tap = 0; tap < 4; ++tap) {
        const int buf = tap & 1;
        if (tap < 3) {              // prefetch next tap into other buffer
            const int ntap = tap + 1;
            const int kh = 2 * (ntap >> 1) + 1 - rh;
            const int kw = 2 * (ntap & 1) + 1 - rw;
            const float* src = Wt + ((kh * 4 + kw) << 12);
            #pragma unroll
            for (int it = 0; it < 4; ++it) {
                int idx = t + (it << 8);
                int ca  = idx >> 3;
                int ci4 = idx & 7;
                float4 wv = *(const float4*)(src + (ca << 5) + (ci4 << 2));
                float* dst = &Wtap[buf ^ 1][(ci4 << 2) * 130 + ca];
                dst[0]   = wv.x;
                dst[130] = wv.y;
                dst[260] = wv.z;
                dst[390] = wv.w;
            }
        }
        // compute this tap: di = uu+1-tkh, dj = vv+1-tkw
        {
            const int tkh = tap >> 1, tkw = tap & 1;
            const int di = uu + 1 - tkh;
            const int dj = vv + 1 - tkw;
            const float* wb = &Wtap[buf][l << 1];
            const float* xb = xs + di * 96 + dj * 32;
            #pragma unroll
            for (int cq = 0; cq < 8; ++cq) {
                float4 xq[8];
                #pragma unroll
                for (int i = 0; i < 8; ++i)
                    xq[i] = *(const float4*)(xb + i * 288 + (cq << 2));
                #pragma unroll
                for (int k = 0; k < 4; ++k) {
                    float2 wv = *(const float2*)(wb + (cq * 4 + k) * 130);
                    #pragma unroll
                    for (int i = 0; i < 8; ++i) {
                        float xv = (&xq[i].x)[k];
                        vo[i].x = fmaf(xv, wv.x, vo[i].x);
                        vo[i].y = fmaf(xv, wv.y, vo[i].y);
                    }
                }
            }
        }
        __syncthreads();
    }

    // ---- dynamic routing, fully in-register (lane: c=l>>3 bits 3..5, a-pair bits 0..2) ----
    float2 bs = *(const float2*)(bias + (l << 1));
    float lg[8];
    #pragma unroll
    for (int i = 0; i < 8; ++i) lg[i] = 0.f;

    float2 act = make_float2(0.f, 0.f);
    #pragma unroll
    for (int r = 0; r < 3; ++r) {
        float route[8];
        if (r == 0) {
            #pragma unroll
            for (int i = 0; i < 8; ++i) route[i] = 0.125f;
        } else {
            #pragma unroll
            for (int i = 0; i < 8; ++i) {
                float m = lg[i];
                m = fmaxf(m, __shfl_xor(m, 8));
                m = fmaxf(m, __shfl_xor(m, 16));
                m = fmaxf(m, __shfl_xor(m, 32));
                float e = __expf(lg[i] - m);
                float s = e;
                s += __shfl_xor(s, 8);
                s += __shfl_xor(s, 16);
                s += __shfl_xor(s, 32);
                route[i] = e / s;
            }
        }
        float2 pre = bs;
        #pragma unroll
        for (int i = 0; i < 8; ++i) {
            pre.x = fmaf(route[i], vo[i].x, pre.x);
            pre.y = fmaf(route[i], vo[i].y, pre.y);
        }
        float sq = pre.x * pre.x + pre.y * pre.y;   // norm^2 over a (16 atoms per c)
        sq += __shfl_xor(sq, 1);
        sq += __shfl_xor(sq, 2);
        sq += __shfl_xor(sq, 4);
        float sc = sq / ((1.f + sq) * sqrtf(sq + CEPS));
        act.x = pre.x * sc;
        act.y = pre.y * sc;
        if (r < 2) {
            #pragma unroll
            for (int i = 0; i < 8; ++i) {
                float d = vo[i].x * act.x + vo[i].y * act.y;
                d += __shfl_xor(d, 1);
                d += __shfl_xor(d, 2);
                d += __shfl_xor(d, 4);
                lg[i] += d;
            }
        }
    }

    const int p = ((u0 + uu) << 1) + rh;
    const int q = ((v0 + vv) << 1) + rw;
    *(float2*)(out + (((bp * 112 + p) * 112 + q) << 7) + (l << 1)) = act;
}

extern "C" void kernel_launch(void* const* d_in, const int* in_sizes, int n_in,
                              void* d_out, int out_size, void* d_ws, size_t ws_size,
                              hipStream_t stream) {
    const float* x  = (const float*)d_in[0];
    const float* Wt = (const float*)d_in[1];
    const float* b  = (const float*)d_in[2];
    float* out = (float*)d_out;
    dim3 grid(784, 4, 4);   // 28x28 2x2-pixel tiles, 4 parity classes, 4 b'
    caps_deconv_routing<<<grid, 256, 0, stream>>>(x, Wt, b, out);
}

// Round 2
// 202.769 us; speedup vs baseline: 1.7316x; 1.7316x over previous
//
#include <hip/hip_runtime.h>
#include <math.h>

#define CEPS 1e-9f

typedef _Float16 half8 __attribute__((ext_vector_type(8)));
typedef float floatx16 __attribute__((ext_vector_type(16)));

// x  : [4,56,56,8,32] fp32    W: [4,4,128,32] fp32    bias: [128] fp32
// out: [4,112,112,128] fp32 act
//
// votes[b'][pix(u,v)][m=(pixl,i)][ca] = sum_{tap,ci} xf[b'][i_pos][j_pos][i][ci] * W[kh][kw][ca][ci]
// with i_pos = u + rh - tkh, j_pos = v + rw - tkw, kh = 2*tkh+1-rh, kw = 2*tkw+1-rw
// xf[b'][h][w][i][ci] = x[i&3][h][w][2b'+(i>>2)][ci]   (reference's reshape scramble)
//
// Wave = M32 MFMA rows (4 pixels along v x 8 i), N=128 (4 tiles of 32 ca), K=128 (8 steps of 16).
// Block = 4 waves = 4x4 pixel tile, one parity class (rh,rw), one b'.

__global__ __launch_bounds__(256, 3) void caps_mfma(
    const float* __restrict__ x,
    const float* __restrict__ Wt,
    const float* __restrict__ bias,
    float* __restrict__ out)
{
    // x tile: [cell(5x5)][i(8)][ci padded 32->40] f16 : i-stride 80B tiles all 32 banks
    __shared__ _Float16 xt[25 * 8 * 40];       // 16000 B
    // W tile: [s(8)][t(4)][lane(64)][8 f16]  — exact B-fragment order, lane-consecutive 16B
    __shared__ _Float16 wt[8 * 4 * 64 * 8];    // 32768 B

    const int tid = threadIdx.x;
    const int tile = blockIdx.x;            // 0..195 : 14x14 tiles of 4x4 pixels
    const int tu = tile / 14, tv = tile - tu * 14;
    const int u0 = tu * 4, v0 = tv * 4;
    const int rh = blockIdx.y >> 1;         // p & 1
    const int rw = blockIdx.y & 1;          // q & 1
    const int bp = blockIdx.z;              // b'

    // ---- stage W: fp32 -> f16 in B-fragment order ----
    // B[k][n], k = s*16 + h*8 + j, n = t*32 + (l&31); tap = s>>1, ci = 16*(s&1)+8h+j
    #pragma unroll
    for (int it = 0; it < 8; ++it) {
        int idx = tid + (it << 8);          // [0,2048)
        int s = idx >> 8;
        int t = (idx >> 6) & 3;
        int l = idx & 63;
        int n = t * 32 + (l & 31);
        int h = l >> 5;
        int ci0 = ((s & 1) << 4) + (h << 3);
        int kh = ((s >> 2) << 1) + 1 - rh;
        int kw = (((s >> 1) & 1) << 1) + 1 - rw;
        const float* src = Wt + (((kh * 4 + kw) * 128 + n) << 5) + ci0;
        float4 w0 = *(const float4*)src;
        float4 w1 = *(const float4*)(src + 4);
        half8 hv;
        hv[0] = (_Float16)w0.x; hv[1] = (_Float16)w0.y;
        hv[2] = (_Float16)w0.z; hv[3] = (_Float16)w0.w;
        hv[4] = (_Float16)w1.x; hv[5] = (_Float16)w1.y;
        hv[6] = (_Float16)w1.z; hv[7] = (_Float16)w1.w;
        *(half8*)(wt + (idx << 3)) = hv;
    }

    // ---- stage x: fp32 -> f16 tile [ri(5)][rj(5)][i(8)][ci], zero-filled OOB ----
    #pragma unroll
    for (int it = 0; it < 4; ++it) {
        int idx = tid + (it << 8);
        if (idx < 800) {
            int cell = idx >> 5;            // 0..24
            int r = idx & 31;
            int i = r >> 2;
            int ci0 = (r & 3) << 3;
            int ri = cell / 5, rj = cell - ri * 5;
            int gi = u0 + rh - 1 + ri;
            int gj = v0 + rw - 1 + rj;
            float tmp[8] = {0.f, 0.f, 0.f, 0.f, 0.f, 0.f, 0.f, 0.f};
            if ((unsigned)gi < 56u && (unsigned)gj < 56u) {
                const float* src = x + (((i & 3) * 56 + gi) * 56 + gj) * 256
                                     + ((bp * 2 + (i >> 2)) << 5) + ci0;
                float4 a0 = *(const float4*)src;
                float4 a1 = *(const float4*)(src + 4);
                tmp[0] = a0.x; tmp[1] = a0.y; tmp[2] = a0.z; tmp[3] = a0.w;
                tmp[4] = a1.x; tmp[5] = a1.y; tmp[6] = a1.z; tmp[7] = a1.w;
            }
            half8 hv;
            #pragma unroll
            for (int j = 0; j < 8; ++j) hv[j] = (_Float16)tmp[j];
            *(half8*)(xt + (cell * 8 + i) * 40 + ci0) = hv;
        }
    }
    __syncthreads();

    const int l = tid & 63;
    const int w = tid >> 6;                 // wave = u-row within tile
    // A-operand lane decomposition: m = l&31 = pixA*8 + iA ; k-half = l>>5
    const int pixA = (l >> 3) & 3;
    const int iA = l & 7;
    const int hA = l >> 5;
    const int invA = (pixA * 8 + iA) * 40 + (hA << 3);   // lane-const, f16 elements

    floatx16 acc[4];
    #pragma unroll
    for (int t = 0; t < 4; ++t)
        #pragma unroll
        for (int j = 0; j < 16; ++j) acc[t][j] = 0.f;

    // ---- MFMA K-loop: 8 k-steps x 4 n-tiles, no barriers ----
    #pragma unroll
    for (int s = 0; s < 8; ++s) {
        const int tkh = s >> 2;
        const int tkw = (s >> 1) & 1;
        const int row = w + 1 - tkh;                      // 5-row tile index
        const int aoff = (row * 5 + 1 - tkw) * 320 + ((s & 1) << 4) + invA;
        half8 af = *(const half8*)(xt + aoff);
        #pragma unroll
        for (int t = 0; t < 4; ++t) {
            half8 bf = *(const half8*)(wt + (((s * 4 + t) * 64 + l) << 3));
            acc[t] = __builtin_amdgcn_mfma_f32_32x32x16_f16(af, bf, acc[t], 0, 0, 0);
        }
    }

    // ---- routing, in-register on C-layout: pix=reg>>2, i=(reg&3)+4*(l>>5), ca=t*32+(l&31) ----
    float bs[4];
    #pragma unroll
    for (int t = 0; t < 4; ++t) bs[t] = bias[t * 32 + (l & 31)];

    #pragma unroll
    for (int pixl = 0; pixl < 4; ++pixl) {
        float v[4][4];                       // [il][t]
        #pragma unroll
        for (int il = 0; il < 4; ++il)
            #pragma unroll
            for (int t = 0; t < 4; ++t) v[il][t] = acc[t][pixl * 4 + il];

        float lg[4][4];
        #pragma unroll
        for (int il = 0; il < 4; ++il)
            #pragma unroll
            for (int t = 0; t < 4; ++t) lg[il][t] = 0.f;

        float actv[4];
        #pragma unroll
        for (int r = 0; r < 3; ++r) {
            float route[4][4];
            if (r == 0) {
                #pragma unroll
                for (int il = 0; il < 4; ++il)
                    #pragma unroll
                    for (int t = 0; t < 4; ++t) route[il][t] = 0.125f;
            } else {
                #pragma unroll
                for (int il = 0; il < 4; ++il) {
                    float m = fmaxf(fmaxf(lg[il][0], lg[il][1]), fmaxf(lg[il][2], lg[il][3]));
                    m = fmaxf(m, __shfl_xor(m, 16));      // other 4 c's
                    float e0 = __expf(lg[il][0] - m);
                    float e1 = __expf(lg[il][1] - m);
                    float e2 = __expf(lg[il][2] - m);
                    float e3 = __expf(lg[il][3] - m);
                    float ss = e0 + e1 + e2 + e3;
                    ss += __shfl_xor(ss, 16);
                    float rs = 1.f / ss;
                    route[il][0] = e0 * rs; route[il][1] = e1 * rs;
                    route[il][2] = e2 * rs; route[il][3] = e3 * rs;
                }
            }
            float act_[4];
            float pre[4];
            #pragma unroll
            for (int t = 0; t < 4; ++t) {
                float p = 0.f;
                #pragma unroll
                for (int il = 0; il < 4; ++il) p = fmaf(route[il][t], v[il][t], p);
                p += __shfl_xor(p, 32);                   // other i-half
                pre[t] = p + bs[t];
            }
            #pragma unroll
            for (int t = 0; t < 4; ++t) {
                float nq = pre[t] * pre[t];               // norm^2 over a (16 lanes)
                nq += __shfl_xor(nq, 1);
                nq += __shfl_xor(nq, 2);
                nq += __shfl_xor(nq, 4);
                nq += __shfl_xor(nq, 8);
                float sc = nq / ((1.f + nq) * sqrtf(nq + CEPS));
                act_[t] = pre[t] * sc;
            }
            if (r < 2) {
                #pragma unroll
                for (int il = 0; il < 4; ++il)
                    #pragma unroll
                    for (int t = 0; t < 4; ++t) {
                        float d = v[il][t] * act_[t];
                        d += __shfl_xor(d, 1);
                        d += __shfl_xor(d, 2);
                        d += __shfl_xor(d, 4);
                        d += __shfl_xor(d, 8);            // d replicated over a-group
                        lg[il][t] += d;
                    }
            } else {
                #pragma unroll
                for (int t = 0; t < 4; ++t) actv[t] = act_[t];
            }
        }

        const int p = ((u0 + w) << 1) + rh;
        const int q = ((v0 + pixl) << 1) + rw;
        float* op = out + (((bp * 112 + p) * 112 + q) << 7) + (l & 31);
        #pragma unroll
        for (int t = 0; t < 4; ++t) op[t << 5] = actv[t];
    }
}

extern "C" void kernel_launch(void* const* d_in, const int* in_sizes, int n_in,
                              void* d_out, int out_size, void* d_ws, size_t ws_size,
                              hipStream_t stream) {
    const float* x  = (const float*)d_in[0];
    const float* Wt = (const float*)d_in[1];
    const float* b  = (const float*)d_in[2];
    float* out = (float*)d_out;
    dim3 grid(196, 4, 4);    // 14x14 4x4-pixel tiles, 4 parity classes, 4 b'
    caps_mfma<<<grid, 256, 0, stream>>>(x, Wt, b, out);
}